// Round 1
// baseline (373.075 us; speedup 1.0000x reference)
//
#include <hip/hip_runtime.h>
#include <math.h>

static constexpr int kN = 8192;
static constexpr int kC = 128;
static constexpr int kB = 16;
static constexpr int kLogN = 13;
static constexpr float kScale = 1.0f / (float)((size_t)kC * kN); // 1/1048576
static constexpr double kTwoPi = 6.28318530717958647692;

__device__ __forceinline__ float2 cmul(float2 a, float2 b) {
    return make_float2(a.x * b.x - a.y * b.y, a.x * b.y + a.y * b.x);
}

// Kernel 1: per (b,c) row.
//  buf <- x_ft row; inverse FFT (DIF radix-2, natural->bitrev, e^{+});
//  take real part; instance-norm + exact GELU (order-agnostic);
//  forward FFT (DIT radix-2, bitrev->natural, e^{-}); store full spectrum.
__global__ __launch_bounds__(256) void k1_row(
    const float* __restrict__ xr, const float* __restrict__ xi,
    const float* __restrict__ gamma, const float* __restrict__ beta,
    float* __restrict__ outR, float* __restrict__ outI)
{
    __shared__ float2 buf[kN];    // 64 KiB
    __shared__ float2 twq[2048];  // 16 KiB: e^{+2pi i j/8192}, j in [0,2048)

    const int tid = threadIdx.x;
    const int row = blockIdx.x;
    const int ch  = row & (kC - 1);

    for (int j = tid; j < 2048; j += 256) {
        float ang = (float)(kTwoPi / 8192.0 * (double)j);
        float s, c;
        sincosf(ang, &s, &c);
        twq[j] = make_float2(c, s);
    }
    const float* rR = xr + (size_t)row * kN;
    const float* rI = xi + (size_t)row * kN;
    for (int i = tid; i < kN; i += 256)
        buf[i] = make_float2(rR[i], rI[i]);
    __syncthreads();

    // ---- inverse FFT, DIF ----
    for (int st = kLogN; st >= 1; --st) {
        const int h = 1 << (st - 1);
        #pragma unroll
        for (int s = 0; s < 16; ++s) {
            int q   = tid + (s << 8);                 // 0..4095
            int pos = q & (h - 1);
            int i0  = ((q >> (st - 1)) << st) + pos;
            int i1  = i0 + h;
            int j   = pos << (kLogN - st);            // < 4096
            float2 t = twq[j & 2047];
            float2 w = (j & 2048) ? make_float2(-t.y, t.x) : t;  // e^{+2pi i j/N}
            float2 a = buf[i0], b = buf[i1];
            buf[i0] = make_float2(a.x + b.x, a.y + b.y);
            float2 d = make_float2(a.x - b.x, a.y - b.y);
            buf[i1] = cmul(d, w);
        }
        __syncthreads();
    }

    // ---- real part + stats (values live in bit-reversed order; stats are
    //      permutation-invariant) ----
    float vals[32];
    float psum = 0.f, psq = 0.f;
    #pragma unroll
    for (int i = 0; i < 32; ++i) {
        float v = buf[tid + (i << 8)].x;
        vals[i] = v;
        psum += v;
        psq  += v * v;
    }
    __syncthreads();   // all reads done before buf[0..3] reused as scratch
    #pragma unroll
    for (int off = 32; off >= 1; off >>= 1) {
        psum += __shfl_down(psum, off);
        psq  += __shfl_down(psq,  off);
    }
    if ((tid & 63) == 0)
        buf[tid >> 6] = make_float2(psum, psq);
    __syncthreads();
    float2 p0 = buf[0], p1 = buf[1], p2 = buf[2], p3 = buf[3];
    float mean = (p0.x + p1.x + p2.x + p3.x) * (1.0f / kN);
    float var  = (p0.y + p1.y + p2.y + p3.y) * (1.0f / kN) - mean * mean;
    float rstd = rsqrtf(var + 1e-5f);
    float g  = gamma[ch] * rstd;
    float bt = beta[ch] - mean * g;        // y = v*g + bt
    __syncthreads();   // stats read before buf overwritten below

    #pragma unroll
    for (int i = 0; i < 32; ++i) {
        float v = vals[i] * g + bt;
        float y = 0.5f * v * (1.0f + erff(v * 0.70710678118654752f)); // exact GELU
        buf[tid + (i << 8)] = make_float2(y, 0.0f);
    }
    __syncthreads();

    // ---- forward FFT, DIT (bitrev input -> natural output) ----
    for (int st = 1; st <= kLogN; ++st) {
        const int h = 1 << (st - 1);
        #pragma unroll
        for (int s = 0; s < 16; ++s) {
            int q   = tid + (s << 8);
            int pos = q & (h - 1);
            int i0  = ((q >> (st - 1)) << st) + pos;
            int i1  = i0 + h;
            int j   = pos << (kLogN - st);
            float2 t = twq[j & 2047];
            float2 w = (j & 2048) ? make_float2(-t.y, t.x) : t;
            w.y = -w.y;                                  // conj: e^{-2pi i j/N}
            float2 a  = buf[i0];
            float2 bw = cmul(buf[i1], w);
            buf[i0] = make_float2(a.x + bw.x, a.y + bw.y);
            buf[i1] = make_float2(a.x - bw.x, a.y - bw.y);
        }
        __syncthreads();
    }

    float* oR = outR + (size_t)row * kN;
    float* oI = outI + (size_t)row * kN;
    for (int i = tid; i < kN; i += 256) {
        float2 v = buf[i];
        oR[i] = v.x;
        oI[i] = v.y;
    }
}

// Kernel 2: per (b, 64-wide k tile): 128-pt forward FFT along channels,
// scale 1/(C*N), then the irfft/fft bin fix-ups. Fully in place on d_out.
__global__ __launch_bounds__(256) void k2_col(float* __restrict__ outR,
                                              float* __restrict__ outI)
{
    __shared__ float2 tile[kC][64];  // 64 KiB, [c][k]
    __shared__ float2 tw[64];        // e^{-2pi i j/128}

    const int tid = threadIdx.x;
    const int b   = blockIdx.x >> 7;
    const int k0  = (blockIdx.x & 127) << 6;
    const int k   = tid & 63;
    const int cq  = tid >> 6;        // 0..3

    if (tid < 64) {
        float ang = (float)(kTwoPi / 128.0 * (double)tid);
        float s, c;
        sincosf(ang, &s, &c);
        tw[tid] = make_float2(c, -s);
    }
    float* baseR = outR + (size_t)b * kC * kN;
    float* baseI = outI + (size_t)b * kC * kN;
    for (int c = cq; c < kC; c += 4) {
        size_t off = (size_t)c * kN + k0 + k;
        tile[c][k] = make_float2(baseR[off], baseI[off]);
    }
    __syncthreads();

    // forward DIF radix-2 along c (natural -> bitrev)
    for (int st = 7; st >= 1; --st) {
        const int h = 1 << (st - 1);
        #pragma unroll
        for (int s = 0; s < 16; ++s) {
            int q   = cq + (s << 2);               // 0..63
            int pos = q & (h - 1);
            int i0  = ((q >> (st - 1)) << st) + pos;
            int i1  = i0 + h;
            float2 a = tile[i0][k], bb = tile[i1][k];
            float2 w = tw[pos << (7 - st)];
            tile[i0][k] = make_float2(a.x + bb.x, a.y + bb.y);
            float2 d = make_float2(a.x - bb.x, a.y - bb.y);
            tile[i1][k] = cmul(d, w);
        }
        __syncthreads();
    }

    // scale + bit-reversed row index + bin rules, written back in place
    for (int p = cq; p < kC; p += 4) {
        int f = (int)(__brev((unsigned)p) >> 25);  // rev7
        float2 v = tile[p][k];
        v.x *= kScale;
        v.y *= kScale;
        int kk = k0 + k;
        int cOut = f;
        if (kk > 4096)                cOut = (kC - f) & (kC - 1); // conj-mirror row
        else if (kk == 0 || kk == 4096) v.y = 0.0f;               // Re-forced bins
        size_t off = (size_t)cOut * kN + kk;
        baseR[off] = v.x;
        baseI[off] = v.y;
    }
}

extern "C" void kernel_launch(void* const* d_in, const int* in_sizes, int n_in,
                              void* d_out, int out_size, void* d_ws, size_t ws_size,
                              hipStream_t stream)
{
    const float* xr    = (const float*)d_in[0];
    const float* xi    = (const float*)d_in[1];
    const float* gamma = (const float*)d_in[2];
    const float* beta  = (const float*)d_in[3];

    float* outR = (float*)d_out;
    float* outI = outR + (size_t)kB * kC * kN;

    k1_row<<<kB * kC, 256, 0, stream>>>(xr, xi, gamma, beta, outR, outI);
    k2_col<<<kB * (kN / 64), 256, 0, stream>>>(outR, outI);
}

// Round 2
// 172.744 us; speedup vs baseline: 2.1597x; 2.1597x over previous
//
#include <hip/hip_runtime.h>
#include <math.h>

static constexpr int kN = 8192;
static constexpr int kC = 128;
static constexpr int kB = 16;
static constexpr float kScale = 1.0f / 1048576.0f; // 1/(C*N)
static constexpr double kTwoPi = 6.28318530717958647692;

#define C8  0.70710678118654752f
#define CP8 0.92387953251128676f
#define SP8 0.38268343236508977f

__device__ __forceinline__ float2 cadd(float2 a, float2 b){ return make_float2(a.x+b.x, a.y+b.y); }
__device__ __forceinline__ float2 csub(float2 a, float2 b){ return make_float2(a.x-b.x, a.y-b.y); }
__device__ __forceinline__ float2 cmul(float2 a, float2 b){ return make_float2(a.x*b.x-a.y*b.y, a.x*b.y+a.y*b.x); }
__device__ __forceinline__ float2 cconj(float2 a){ return make_float2(a.x, -a.y); }

__device__ __forceinline__ int swz(int n){ return n ^ ((n>>4)&15); }

// T[m] = e^{+2pi i m/4096}, m in [0,1024), stored swizzled
__device__ __forceinline__ float2 Tld(const float2* T, int m){ return T[m ^ ((m>>4)&15)]; }
// e^{+2pi i m/4096}, m in [0,2048)
__device__ __forceinline__ float2 Tld2(const float2* T, int m){
    int lo = m & 1023;
    float2 t = T[lo ^ ((lo>>4)&15)];
    if (m & 1024) t = make_float2(-t.y, t.x);
    return t;
}

// radix-4 DIF butterfly, sigma=+1 (inverse / e^{+})
__device__ __forceinline__ void bfly_dif_p(float2&a,float2&b,float2&c,float2&d,
                                           float2 w1,float2 w2,float2 w3){
    float2 t0=cadd(a,c), t1=csub(a,c), t2=cadd(b,d), bd=csub(b,d);
    float2 t3=make_float2(-bd.y, bd.x);            // +i(b-d)
    a=cadd(t0,t2);
    b=cmul(cadd(t1,t3),w1);
    c=cmul(csub(t0,t2),w2);
    d=cmul(csub(t1,t3),w3);
}
__device__ __forceinline__ void bfly_dif_p_nt(float2&a,float2&b,float2&c,float2&d){
    float2 t0=cadd(a,c), t1=csub(a,c), t2=cadd(b,d), bd=csub(b,d);
    float2 t3=make_float2(-bd.y, bd.x);
    a=cadd(t0,t2); b=cadd(t1,t3); c=csub(t0,t2); d=csub(t1,t3);
}
// radix-4 DIT butterfly, sigma=-1 (forward / e^{-})
__device__ __forceinline__ void bfly_dit_m(float2&a,float2&b,float2&c,float2&d,
                                           float2 w1,float2 w2,float2 w3){
    float2 bt=cmul(b,w1), ct=cmul(c,w2), dt=cmul(d,w3);
    float2 s0=cadd(a,ct), s1=csub(a,ct), s2=cadd(bt,dt), bd=csub(bt,dt);
    float2 u=make_float2(bd.y, -bd.x);             // -i(bt-dt)
    a=cadd(s0,s2); b=cadd(s1,u); c=csub(s0,s2); d=csub(s1,u);
}
__device__ __forceinline__ void bfly_dit_m_nt(float2&a,float2&b,float2&c,float2&d){
    float2 s0=cadd(a,c), s1=csub(a,c), s2=cadd(b,d), bd=csub(b,d);
    float2 u=make_float2(bd.y, -bd.x);
    a=cadd(s0,s2); b=cadd(s1,u); c=csub(s0,s2); d=csub(s1,u);
}

__device__ __forceinline__ float gelu_exact(float v){
    return 0.5f * v * (1.0f + erff(v * 0.70710678118654752f));
}

// Kernel 1: per (b,c) row. Hermitian-pack -> 4096-pt inverse FFT (3 register
// phases, radix-4^2 each) -> instnorm+GELU in regs -> 4096-pt forward FFT ->
// rfft post-combine -> store half spectrum Y[0..4096].
__global__ __launch_bounds__(256,4) void k1_row(
    const float* __restrict__ xr, const float* __restrict__ xi,
    const float* __restrict__ gamma, const float* __restrict__ beta,
    float* __restrict__ outR, float* __restrict__ outI)
{
    __shared__ float2 buf[4096];   // 32 KiB, swizzled
    __shared__ float2 T[1024];     // 8 KiB quarter twiddle, swizzled

    const int t   = threadIdx.x;
    const int row = blockIdx.x;
    const int ch  = row & (kC-1);
    const int r   = t & 15;
    const int Bq  = ((t>>4)<<8) + r;   // 256*(t>>4) + (t&15)

    for (int i = t; i < 1024; i += 256) {
        float s, c;
        sincosf((float)(kTwoPi/4096.0 * (double)i), &s, &c);
        T[i ^ ((i>>4)&15)] = make_float2(c, s);
    }
    __syncthreads();

    const float* rR = xr + (size_t)row * kN;
    const float* rI = xi + (size_t)row * kN;

    // ---- pre: Z[k] = (H[k]+H[k+2048*2]) + i e^{+2pi i k/8192}(H[k]-H[k+4096])
    const float2 E = make_float2(0.99999970586f, 7.6699031871e-4f); // e^{+i pi/4096}
    float2 v[16];
    #pragma unroll
    for (int j = 0; j < 16; ++j) {
        int k = t + (j<<8);
        float2 Xk  = make_float2(rR[k], rI[k]);
        int km  = (kN - k) & (kN-1);
        float2 Xm  = make_float2(rR[km], rI[km]);
        float2 Hk  = make_float2(0.5f*(Xk.x+Xm.x), 0.5f*(Xk.y-Xm.y));
        float2 Xk2 = make_float2(rR[k+4096], rI[k+4096]);
        int km2 = 4096 - k;
        float2 Xm2 = make_float2(rR[km2], rI[km2]);
        float2 Hk2 = make_float2(0.5f*(Xk2.x+Xm2.x), 0.5f*(Xk2.y-Xm2.y));
        float2 S = cadd(Hk,Hk2), D = csub(Hk,Hk2);
        float2 w = Tld2(T, k>>1);
        if (t & 1) w = cmul(w, E);                  // e^{+i pi k/4096}
        float2 P = cmul(D, w);
        v[j] = make_float2(S.x - P.y, S.y + P.x);   // S + i*P
    }

    // ---- inverse FFT: DIF, sigma=+1 ----
    // Phase A (regs): L=1024 then L=256
    #pragma unroll
    for (int j0 = 0; j0 < 4; ++j0) {
        float2 w1 = Tld(T, t + (j0<<8));
        float2 w2 = cmul(w1,w1), w3 = cmul(w2,w1);
        bfly_dif_p(v[j0], v[j0+4], v[j0+8], v[j0+12], w1,w2,w3);
    }
    {
        float2 w1 = Tld(T, 4*t);
        float2 w2 = cmul(w1,w1), w3 = cmul(w2,w1);
        #pragma unroll
        for (int b4 = 0; b4 < 4; ++b4)
            bfly_dif_p(v[4*b4], v[4*b4+1], v[4*b4+2], v[4*b4+3], w1,w2,w3);
    }
    #pragma unroll
    for (int j = 0; j < 16; ++j) buf[swz(t + (j<<8))] = v[j];
    __syncthreads();

    // Phase B: L=64 then L=16
    #pragma unroll
    for (int j = 0; j < 16; ++j) v[j] = buf[swz(Bq + (j<<4))];
    #pragma unroll
    for (int j0 = 0; j0 < 4; ++j0) {
        float2 w1 = Tld(T, 16*((j0<<4) + r));
        float2 w2 = cmul(w1,w1), w3 = cmul(w2,w1);
        bfly_dif_p(v[j0], v[j0+4], v[j0+8], v[j0+12], w1,w2,w3);
    }
    {
        float2 w1 = Tld(T, 64*r);
        float2 w2 = cmul(w1,w1), w3 = cmul(w2,w1);
        #pragma unroll
        for (int b4 = 0; b4 < 4; ++b4)
            bfly_dif_p(v[4*b4], v[4*b4+1], v[4*b4+2], v[4*b4+3], w1,w2,w3);
    }
    #pragma unroll
    for (int j = 0; j < 16; ++j) buf[swz(Bq + (j<<4))] = v[j];
    __syncthreads();

    // Phase C: L=4 (const tw) then L=1
    #pragma unroll
    for (int j = 0; j < 16; ++j) v[j] = buf[swz((t<<4) + j)];
    bfly_dif_p_nt(v[0], v[4], v[8], v[12]);
    bfly_dif_p(v[1], v[5], v[9],  v[13], make_float2(CP8,SP8),  make_float2(C8,C8),    make_float2(SP8,CP8));
    bfly_dif_p(v[2], v[6], v[10], v[14], make_float2(C8,C8),    make_float2(0.f,1.f),  make_float2(-C8,C8));
    bfly_dif_p(v[3], v[7], v[11], v[15], make_float2(SP8,CP8),  make_float2(-C8,C8),   make_float2(-CP8,-SP8));
    #pragma unroll
    for (int b4 = 0; b4 < 4; ++b4)
        bfly_dif_p_nt(v[4*b4], v[4*b4+1], v[4*b4+2], v[4*b4+3]);

    // ---- instance norm + GELU (order-agnostic) ----
    float psum = 0.f, psq = 0.f;
    #pragma unroll
    for (int j = 0; j < 16; ++j) {
        psum += v[j].x + v[j].y;
        psq  += v[j].x*v[j].x + v[j].y*v[j].y;
    }
    __syncthreads();                       // all C-phase buf reads complete
    #pragma unroll
    for (int off = 32; off >= 1; off >>= 1) {
        psum += __shfl_down(psum, off);
        psq  += __shfl_down(psq,  off);
    }
    if ((t & 63) == 0) buf[t>>6] = make_float2(psum, psq);
    __syncthreads();
    float2 q0 = buf[0], q1 = buf[1], q2 = buf[2], q3 = buf[3];
    __syncthreads();                       // stats read before buf reuse
    float mean = (q0.x+q1.x+q2.x+q3.x) * (1.0f/8192.0f);
    float var  = (q0.y+q1.y+q2.y+q3.y) * (1.0f/8192.0f) - mean*mean;
    float rstd = rsqrtf(var + 1e-5f);
    float g  = gamma[ch] * rstd;
    float bt = beta[ch] - mean * g;
    #pragma unroll
    for (int j = 0; j < 16; ++j) {
        v[j].x = gelu_exact(v[j].x * g + bt);
        v[j].y = gelu_exact(v[j].y * g + bt);
    }

    // ---- forward FFT: DIT, sigma=-1 ----
    // Phase C': L=1 then L=4 (const tw)
    #pragma unroll
    for (int b4 = 0; b4 < 4; ++b4)
        bfly_dit_m_nt(v[4*b4], v[4*b4+1], v[4*b4+2], v[4*b4+3]);
    bfly_dit_m_nt(v[0], v[4], v[8], v[12]);
    bfly_dit_m(v[1], v[5], v[9],  v[13], make_float2(CP8,-SP8), make_float2(C8,-C8),   make_float2(SP8,-CP8));
    bfly_dit_m(v[2], v[6], v[10], v[14], make_float2(C8,-C8),   make_float2(0.f,-1.f), make_float2(-C8,-C8));
    bfly_dit_m(v[3], v[7], v[11], v[15], make_float2(SP8,-CP8), make_float2(-C8,-C8),  make_float2(-CP8,SP8));
    #pragma unroll
    for (int j = 0; j < 16; ++j) buf[swz((t<<4) + j)] = v[j];
    __syncthreads();

    // Phase B': L=16 then L=64
    #pragma unroll
    for (int j = 0; j < 16; ++j) v[j] = buf[swz(Bq + (j<<4))];
    {
        float2 w1 = cconj(Tld(T, 64*r));
        float2 w2 = cmul(w1,w1), w3 = cmul(w2,w1);
        #pragma unroll
        for (int b4 = 0; b4 < 4; ++b4)
            bfly_dit_m(v[4*b4], v[4*b4+1], v[4*b4+2], v[4*b4+3], w1,w2,w3);
    }
    #pragma unroll
    for (int j0 = 0; j0 < 4; ++j0) {
        float2 w1 = cconj(Tld(T, 16*((j0<<4) + r)));
        float2 w2 = cmul(w1,w1), w3 = cmul(w2,w1);
        bfly_dit_m(v[j0], v[j0+4], v[j0+8], v[j0+12], w1,w2,w3);
    }
    #pragma unroll
    for (int j = 0; j < 16; ++j) buf[swz(Bq + (j<<4))] = v[j];
    __syncthreads();

    // Phase A': L=256 then L=1024; result Z'[t+256j] natural order
    #pragma unroll
    for (int j = 0; j < 16; ++j) v[j] = buf[swz(t + (j<<8))];
    {
        float2 w1 = cconj(Tld(T, 4*t));
        float2 w2 = cmul(w1,w1), w3 = cmul(w2,w1);
        #pragma unroll
        for (int b4 = 0; b4 < 4; ++b4)
            bfly_dit_m(v[4*b4], v[4*b4+1], v[4*b4+2], v[4*b4+3], w1,w2,w3);
    }
    #pragma unroll
    for (int j0 = 0; j0 < 4; ++j0) {
        float2 w1 = cconj(Tld(T, t + (j0<<8)));
        float2 w2 = cmul(w1,w1), w3 = cmul(w2,w1);
        bfly_dit_m(v[j0], v[j0+4], v[j0+8], v[j0+12], w1,w2,w3);
    }
    #pragma unroll
    for (int j = 0; j < 16; ++j) buf[swz(t + (j<<8))] = v[j];
    __syncthreads();

    // ---- post: Y[k] = S - i e^{-2pi i k/8192} D ; store half spectrum ----
    float* oR = outR + (size_t)row * kN;
    float* oI = outI + (size_t)row * kN;
    #pragma unroll
    for (int j = 0; j < 16; ++j) {
        int k = t + (j<<8);
        float2 Z  = v[j];
        float2 Zm = buf[swz((4096 - k) & 4095)];
        float2 S = make_float2(0.5f*(Z.x+Zm.x), 0.5f*(Z.y-Zm.y));
        float2 D = make_float2(0.5f*(Z.x-Zm.x), 0.5f*(Z.y+Zm.y));
        float2 w = Tld2(T, k>>1);
        if (t & 1) w = cmul(w, E);
        w = cconj(w);                                // e^{-i pi k/4096}
        float2 P = cmul(D, w);
        oR[k] = S.x + P.y;
        oI[k] = S.y - P.x;
    }
    if (t == 0) {
        oR[4096] = v[0].x - v[0].y;                  // Y[N/2] = Re Z'[0] - Im Z'[0]
        oI[4096] = 0.f;
    }
}

// Kernel 2: per (b, 32-wide k tile), kk in [0,4096]: 128-pt FFT along c,
// scale, bin rules, and conjugate mirror writes for kk in [1,4095].
__global__ __launch_bounds__(256,4) void k2_col(float* __restrict__ outR,
                                                float* __restrict__ outI)
{
    __shared__ float2 tile[kC][32];  // 32 KiB
    __shared__ float2 tw[64];

    const int tid = threadIdx.x;
    const int k   = tid & 31;
    const int g   = tid >> 5;        // 0..7
    const int b   = blockIdx.y;
    const int kk  = (blockIdx.x << 5) + k;
    const bool valid = (kk <= 4096);

    if (tid < 64) {
        float s, c;
        sincosf((float)(kTwoPi/128.0 * (double)tid), &s, &c);
        tw[tid] = make_float2(c, -s);
    }
    float* baseR = outR + (size_t)b * kC * kN;
    float* baseI = outI + (size_t)b * kC * kN;
    for (int c = g; c < kC; c += 8) {
        size_t off = (size_t)c * kN + kk;
        tile[c][k] = valid ? make_float2(baseR[off], baseI[off])
                           : make_float2(0.f, 0.f);
    }
    __syncthreads();

    for (int st = 7; st >= 1; --st) {
        const int h = 1 << (st-1);
        #pragma unroll
        for (int s = 0; s < 8; ++s) {
            int q   = g + (s<<3);
            int pos = q & (h-1);
            int i0  = ((q >> (st-1)) << st) + pos;
            int i1  = i0 + h;
            float2 a = tile[i0][k], bb = tile[i1][k];
            float2 w = tw[pos << (7-st)];
            tile[i0][k] = cadd(a, bb);
            tile[i1][k] = cmul(csub(a, bb), w);
        }
        __syncthreads();
    }

    if (valid) {
        for (int p = g; p < kC; p += 8) {
            int f = (int)(__brev((unsigned)p) >> 25);
            float2 v = tile[p][k];
            v.x *= kScale; v.y *= kScale;
            size_t off = (size_t)f * kN + kk;
            if (kk == 0 || kk == 4096) {
                baseR[off] = v.x; baseI[off] = 0.f;
            } else {
                baseR[off] = v.x; baseI[off] = v.y;
                size_t offm = (size_t)f * kN + (kN - kk);
                baseR[offm] = v.x; baseI[offm] = -v.y;
            }
        }
    }
}

extern "C" void kernel_launch(void* const* d_in, const int* in_sizes, int n_in,
                              void* d_out, int out_size, void* d_ws, size_t ws_size,
                              hipStream_t stream)
{
    const float* xr    = (const float*)d_in[0];
    const float* xi    = (const float*)d_in[1];
    const float* gamma = (const float*)d_in[2];
    const float* beta  = (const float*)d_in[3];

    float* outR = (float*)d_out;
    float* outI = outR + (size_t)kB * kC * kN;

    k1_row<<<kB * kC, 256, 0, stream>>>(xr, xi, gamma, beta, outR, outI);
    k2_col<<<dim3(129, kB), 256, 0, stream>>>(outR, outI);
}

// Round 3
// 162.710 us; speedup vs baseline: 2.2929x; 1.0617x over previous
//
#include <hip/hip_runtime.h>
#include <math.h>

static constexpr int kN = 8192;
static constexpr int kC = 128;
static constexpr int kB = 16;
static constexpr float kScale = 1.0f / 1048576.0f; // 1/(C*N)
static constexpr double kTwoPi = 6.28318530717958647692;

#define C8 0.70710678118654752f

__device__ __forceinline__ float2 cadd(float2 a, float2 b){ return make_float2(a.x+b.x, a.y+b.y); }
__device__ __forceinline__ float2 csub(float2 a, float2 b){ return make_float2(a.x-b.x, a.y-b.y); }
__device__ __forceinline__ float2 cmul(float2 a, float2 b){ return make_float2(a.x*b.x-a.y*b.y, a.x*b.y+a.y*b.x); }
__device__ __forceinline__ float2 cconj(float2 a){ return make_float2(a.x, -a.y); }

// conflict-floor swizzle: bijective, keeps all 4 stage patterns at the b64 minimum
__device__ __forceinline__ int swz(int n){ return n ^ ((n>>4)&7) ^ (((n>>6)&7)<<3); }

// e^{+2pi i m/4096}, m in [0,2048)
__device__ __forceinline__ float2 W2048(const float2* T, int m){
    float2 tt = T[m & 1023];
    return (m & 1024) ? make_float2(-tt.y, tt.x) : tt;
}

// 8-point DFT, A_k = sum_j a_j e^{SGN*2pi i jk/8}, in place (index j -> k)
template<int SGN>
__device__ __forceinline__ void dft8(float2* a){
    float2 s0=cadd(a[0],a[4]), s1=csub(a[0],a[4]);
    float2 s2=cadd(a[2],a[6]), s3=csub(a[2],a[6]);
    float2 E0=cadd(s0,s2), E2=csub(s0,s2);
    float2 j3 = (SGN>0)? make_float2(-s3.y, s3.x) : make_float2(s3.y, -s3.x);
    float2 E1=cadd(s1,j3), E3=csub(s1,j3);
    float2 t0=cadd(a[1],a[5]), t1=csub(a[1],a[5]);
    float2 t2=cadd(a[3],a[7]), t3=csub(a[3],a[7]);
    float2 O0=cadd(t0,t2), O2=csub(t0,t2);
    float2 k3 = (SGN>0)? make_float2(-t3.y, t3.x) : make_float2(t3.y, -t3.x);
    float2 O1=cadd(t1,k3), O3=csub(t1,k3);
    float2 W1 = (SGN>0)? make_float2(C8*(O1.x-O1.y), C8*(O1.x+O1.y))
                       : make_float2(C8*(O1.x+O1.y), C8*(O1.y-O1.x));
    float2 W2 = (SGN>0)? make_float2(-O2.y, O2.x) : make_float2(O2.y, -O2.x);
    float2 W3 = (SGN>0)? make_float2(C8*(-O3.x-O3.y), C8*(O3.x-O3.y))
                       : make_float2(C8*(O3.y-O3.x), C8*(-O3.x-O3.y));
    a[0]=cadd(E0,O0); a[4]=csub(E0,O0);
    a[1]=cadd(E1,W1); a[5]=csub(E1,W1);
    a[2]=cadd(E2,W2); a[6]=csub(E2,W2);
    a[3]=cadd(E3,W3); a[7]=csub(E3,W3);
}

// tanh-form GELU: v * sigmoid(2z), z = sqrt(2/pi)(v + 0.044715 v^3)
__device__ __forceinline__ float gelu_fast(float v){
    float z = v*(0.7978845608028654f + 0.0356774081363001f*v*v);
    float e = __builtin_amdgcn_exp2f(-2.8853900817779268f * z); // e^{-2z}
    return v / (1.0f + e);
}

// Kernel 1: per (b,c) row. Hermitian-pack -> 4096-pt inverse FFT (radix-8^4,
// DIF) -> instnorm + GELU in regs -> forward FFT (radix-8^4, DIT) -> rfft
// post-combine -> store half spectrum Y[0..4096].
__global__ __launch_bounds__(512, 8) void k1_row(
    const float* __restrict__ xr, const float* __restrict__ xi,
    const float* __restrict__ gamma, const float* __restrict__ beta,
    float* __restrict__ outR, float* __restrict__ outI)
{
    __shared__ float2 buf[4096];  // 32 KiB, swizzled
    __shared__ float2 T[1024];    // 8 KiB: e^{+2pi i m/4096}, m<1024

    const int t   = threadIdx.x;
    const int row = blockIdx.x;
    const int ch  = row & (kC-1);

    for (int i = t; i < 1024; i += 512) {
        float s, c;
        sincosf((float)(kTwoPi/4096.0 * (double)i), &s, &c);
        T[i] = make_float2(c, s);
    }
    __syncthreads();

    const float* rR = xr + (size_t)row * kN;
    const float* rI = xi + (size_t)row * kN;

    // ---- pre-combine: Z[k] = H[k]+H[k+4096] + i e^{+i pi k/4096}(H[k]-H[k+4096])
    const float2 E = make_float2(0.9999997058628822f, 7.669903187427045e-4f); // e^{+i pi/4096}
    float2 v[8];
    #pragma unroll
    for (int j = 0; j < 8; ++j) {
        int k = t + (j<<9);
        float2 Xk  = make_float2(rR[k], rI[k]);
        int km  = (kN - k) & (kN-1);
        float2 Xm  = make_float2(rR[km], rI[km]);
        float2 Hk  = make_float2(0.5f*(Xk.x+Xm.x), 0.5f*(Xk.y-Xm.y));
        float2 Xk2 = make_float2(rR[k+4096], rI[k+4096]);
        int km2 = 4096 - k;
        float2 Xm2 = make_float2(rR[km2], rI[km2]);
        float2 Hk2 = make_float2(0.5f*(Xk2.x+Xm2.x), 0.5f*(Xk2.y-Xm2.y));
        float2 S = cadd(Hk,Hk2), D = csub(Hk,Hk2);
        float2 w = W2048(T, k>>1);
        if (t & 1) w = cmul(w, E);
        float2 P = cmul(D, w);
        v[j] = make_float2(S.x - P.y, S.y + P.x);   // S + i*P
    }

    // ======== inverse FFT: DIF radix-8, stages h = 512,64,8,1, sigma=+1 ======
    // stage h=512 (fused with pre-combine; thread owns its 8 slots)
    dft8<1>(v);
    {
        float2 w1 = T[t], w = w1;
        #pragma unroll
        for (int k = 1; k < 8; ++k){ v[k] = cmul(v[k], w); if (k < 7) w = cmul(w, w1); }
        int s0 = swz(t);
        #pragma unroll
        for (int j = 0; j < 8; ++j) buf[s0 + (j<<9)] = v[j];
    }
    __syncthreads();
    // stage h=64
    const int l  = t & 63, Bq = t >> 6;
    const int s64 = (Bq*512 + l) ^ (l>>4);
    {
        #pragma unroll
        for (int j = 0; j < 8; ++j) v[j] = buf[s64 ^ ((j<<6)|(j<<3)|((j&1)<<2))];
        dft8<1>(v);
        float2 w1 = T[l<<3], w = w1;
        #pragma unroll
        for (int k = 1; k < 8; ++k){ v[k] = cmul(v[k], w); if (k < 7) w = cmul(w, w1); }
        #pragma unroll
        for (int j = 0; j < 8; ++j) buf[s64 ^ ((j<<6)|(j<<3)|((j&1)<<2))] = v[j];
    }
    __syncthreads();
    // stage h=8
    const int u = t & 7, G = t >> 3, g = G & 7;
    const int s8 = (G<<6) + (g<<3) + (u ^ ((G&1)<<2));
    {
        #pragma unroll
        for (int j = 0; j < 8; ++j) v[j] = buf[s8 ^ ((j<<3)|(j>>1))];
        dft8<1>(v);
        float2 w1 = T[u<<6], w = w1;
        #pragma unroll
        for (int k = 1; k < 8; ++k){ v[k] = cmul(v[k], w); if (k < 7) w = cmul(w, w1); }
        #pragma unroll
        for (int j = 0; j < 8; ++j) buf[s8 ^ ((j<<3)|(j>>1))] = v[j];
    }
    __syncthreads();
    // stage h=1 (no twiddle, no store: feeds elementwise + DIT h=1 directly)
    const int s1 = (t<<3) ^ ((t>>1)&7) ^ (((t>>3)&7)<<3);
    #pragma unroll
    for (int j = 0; j < 8; ++j) v[j] = buf[s1 ^ j];
    dft8<1>(v);

    // ---- instance norm + GELU (digit-reversed order: permutation-invariant)
    float psum = 0.f, psq = 0.f;
    #pragma unroll
    for (int j = 0; j < 8; ++j) {
        psum += v[j].x + v[j].y;
        psq  += v[j].x*v[j].x + v[j].y*v[j].y;
    }
    #pragma unroll
    for (int off = 32; off >= 1; off >>= 1) {
        psum += __shfl_down(psum, off);
        psq  += __shfl_down(psq,  off);
    }
    // wave leader writes its OWN h=1 slot (S(512w)=512w) -> no pre-barrier needed
    if ((t & 63) == 0) buf[(t>>6)<<9] = make_float2(psum, psq);
    __syncthreads();
    float sum = 0.f, sq = 0.f;
    #pragma unroll
    for (int w = 0; w < 8; ++w) { float2 p = buf[w<<9]; sum += p.x; sq += p.y; }
    __syncthreads();   // partial reads done before DIT h=1 stores
    float mean = sum * (1.0f/8192.0f);
    float var  = sq  * (1.0f/8192.0f) - mean*mean;
    float rstd = rsqrtf(var + 1e-5f);
    float gg = gamma[ch] * rstd;
    float bb = beta[ch] - mean * gg;
    #pragma unroll
    for (int j = 0; j < 8; ++j) {
        v[j].x = gelu_fast(v[j].x * gg + bb);
        v[j].y = gelu_fast(v[j].y * gg + bb);
    }

    // ======== forward FFT: DIT radix-8, stages h = 1,8,64,512, sigma=-1 =====
    dft8<-1>(v);
    #pragma unroll
    for (int j = 0; j < 8; ++j) buf[s1 ^ j] = v[j];
    __syncthreads();
    // stage h=8
    {
        #pragma unroll
        for (int k = 0; k < 8; ++k) v[k] = buf[s8 ^ ((k<<3)|(k>>1))];
        float2 w1 = cconj(T[u<<6]), w = w1;
        #pragma unroll
        for (int k = 1; k < 8; ++k){ v[k] = cmul(v[k], w); if (k < 7) w = cmul(w, w1); }
        dft8<-1>(v);
        #pragma unroll
        for (int j = 0; j < 8; ++j) buf[s8 ^ ((j<<3)|(j>>1))] = v[j];
    }
    __syncthreads();
    // stage h=64
    {
        #pragma unroll
        for (int k = 0; k < 8; ++k) v[k] = buf[s64 ^ ((k<<6)|(k<<3)|((k&1)<<2))];
        float2 w1 = cconj(T[l<<3]), w = w1;
        #pragma unroll
        for (int k = 1; k < 8; ++k){ v[k] = cmul(v[k], w); if (k < 7) w = cmul(w, w1); }
        dft8<-1>(v);
        #pragma unroll
        for (int j = 0; j < 8; ++j) buf[s64 ^ ((j<<6)|(j<<3)|((j&1)<<2))] = v[j];
    }
    __syncthreads();
    // stage h=512: output Z'[t+512j] natural order, kept in regs + stored for mirror
    {
        int s0 = swz(t);
        #pragma unroll
        for (int k = 0; k < 8; ++k) v[k] = buf[s0 + (k<<9)];
        float2 w1 = cconj(T[t]), w = w1;
        #pragma unroll
        for (int k = 1; k < 8; ++k){ v[k] = cmul(v[k], w); if (k < 7) w = cmul(w, w1); }
        dft8<-1>(v);
        #pragma unroll
        for (int j = 0; j < 8; ++j) buf[s0 + (j<<9)] = v[j];
    }
    __syncthreads();

    // ---- post-combine: Y[k] = S - i e^{-i pi k/4096} D; store Y[0..4095], Y[4096]
    float* oR = outR + (size_t)row * kN;
    float* oI = outI + (size_t)row * kN;
    #pragma unroll
    for (int j = 0; j < 8; ++j) {
        int k = t + (j<<9);
        float2 Z  = v[j];
        float2 Zm = buf[swz((4096 - k) & 4095)];
        float2 S = make_float2(0.5f*(Z.x+Zm.x), 0.5f*(Z.y-Zm.y));
        float2 D = make_float2(0.5f*(Z.x-Zm.x), 0.5f*(Z.y+Zm.y));
        float2 w = W2048(T, k>>1);
        if (t & 1) w = cmul(w, E);
        w = cconj(w);
        float2 P = cmul(D, w);
        oR[k] = S.x + P.y;
        oI[k] = S.y - P.x;
    }
    if (t == 0) {
        oR[4096] = v[0].x - v[0].y;   // Y[N/2] = Re Z'[0] - Im Z'[0]
        oI[4096] = 0.f;
    }
}

// Kernel 2: per (b, 32-wide k tile), kk in [0,4096]: 128-pt FFT along c,
// scale, bin rules, conjugate-mirror writes. Unchanged (≈84% of HBM roofline).
__global__ __launch_bounds__(256,4) void k2_col(float* __restrict__ outR,
                                                float* __restrict__ outI)
{
    __shared__ float2 tile[kC][32];  // 32 KiB
    __shared__ float2 tw[64];

    const int tid = threadIdx.x;
    const int k   = tid & 31;
    const int g   = tid >> 5;        // 0..7
    const int b   = blockIdx.y;
    const int kk  = (blockIdx.x << 5) + k;
    const bool valid = (kk <= 4096);

    if (tid < 64) {
        float s, c;
        sincosf((float)(kTwoPi/128.0 * (double)tid), &s, &c);
        tw[tid] = make_float2(c, -s);
    }
    float* baseR = outR + (size_t)b * kC * kN;
    float* baseI = outI + (size_t)b * kC * kN;
    for (int c = g; c < kC; c += 8) {
        size_t off = (size_t)c * kN + kk;
        tile[c][k] = valid ? make_float2(baseR[off], baseI[off])
                           : make_float2(0.f, 0.f);
    }
    __syncthreads();

    for (int st = 7; st >= 1; --st) {
        const int h = 1 << (st-1);
        #pragma unroll
        for (int s = 0; s < 8; ++s) {
            int q   = g + (s<<3);
            int pos = q & (h-1);
            int i0  = ((q >> (st-1)) << st) + pos;
            int i1  = i0 + h;
            float2 a = tile[i0][k], bb = tile[i1][k];
            float2 w = tw[pos << (7-st)];
            tile[i0][k] = cadd(a, bb);
            tile[i1][k] = cmul(csub(a, bb), w);
        }
        __syncthreads();
    }

    if (valid) {
        for (int p = g; p < kC; p += 8) {
            int f = (int)(__brev((unsigned)p) >> 25);
            float2 v = tile[p][k];
            v.x *= kScale; v.y *= kScale;
            size_t off = (size_t)f * kN + kk;
            if (kk == 0 || kk == 4096) {
                baseR[off] = v.x; baseI[off] = 0.f;
            } else {
                baseR[off] = v.x; baseI[off] = v.y;
                size_t offm = (size_t)f * kN + (kN - kk);
                baseR[offm] = v.x; baseI[offm] = -v.y;
            }
        }
    }
}

extern "C" void kernel_launch(void* const* d_in, const int* in_sizes, int n_in,
                              void* d_out, int out_size, void* d_ws, size_t ws_size,
                              hipStream_t stream)
{
    const float* xr    = (const float*)d_in[0];
    const float* xi    = (const float*)d_in[1];
    const float* gamma = (const float*)d_in[2];
    const float* beta  = (const float*)d_in[3];

    float* outR = (float*)d_out;
    float* outI = outR + (size_t)kB * kC * kN;

    k1_row<<<kB * kC, 512, 0, stream>>>(xr, xi, gamma, beta, outR, outI);
    k2_col<<<dim3(129, kB), 256, 0, stream>>>(outR, outI);
}

// Round 4
// 124.594 us; speedup vs baseline: 2.9943x; 1.3059x over previous
//
#include <hip/hip_runtime.h>
#include <math.h>

static constexpr int kN = 8192;
static constexpr int kC = 128;
static constexpr int kB = 16;
static constexpr float kScale = 0.5f / 1048576.0f; // 1/(C*N) * 0.5 (post-combine fold)
static constexpr double kTwoPi = 6.28318530717958647692;

#define C8 0.70710678118654752f

__device__ __forceinline__ float2 cadd(float2 a, float2 b){ return make_float2(a.x+b.x, a.y+b.y); }
__device__ __forceinline__ float2 csub(float2 a, float2 b){ return make_float2(a.x-b.x, a.y-b.y); }
__device__ __forceinline__ float2 cmul(float2 a, float2 b){ return make_float2(a.x*b.x-a.y*b.y, a.x*b.y+a.y*b.x); }
__device__ __forceinline__ float2 cconj(float2 a){ return make_float2(a.x, -a.y); }

// conflict-floor swizzle (validated r3)
__device__ __forceinline__ int swz(int n){ return n ^ ((n>>4)&7) ^ (((n>>6)&7)<<3); }

// e^{+2pi i m/4096}, m in [0,2048)
__device__ __forceinline__ float2 W2048(const float2* T, int m){
    float2 tt = T[m & 1023];
    return (m & 1024) ? make_float2(-tt.y, tt.x) : tt;
}

// 8-point DFT, A_k = sum_j a_j e^{SGN*2pi i jk/8}, in place
template<int SGN>
__device__ __forceinline__ void dft8(float2* a){
    float2 s0=cadd(a[0],a[4]), s1=csub(a[0],a[4]);
    float2 s2=cadd(a[2],a[6]), s3=csub(a[2],a[6]);
    float2 E0=cadd(s0,s2), E2=csub(s0,s2);
    float2 j3 = (SGN>0)? make_float2(-s3.y, s3.x) : make_float2(s3.y, -s3.x);
    float2 E1=cadd(s1,j3), E3=csub(s1,j3);
    float2 t0=cadd(a[1],a[5]), t1=csub(a[1],a[5]);
    float2 t2=cadd(a[3],a[7]), t3=csub(a[3],a[7]);
    float2 O0=cadd(t0,t2), O2=csub(t0,t2);
    float2 k3 = (SGN>0)? make_float2(-t3.y, t3.x) : make_float2(t3.y, -t3.x);
    float2 O1=cadd(t1,k3), O3=csub(t1,k3);
    float2 W1 = (SGN>0)? make_float2(C8*(O1.x-O1.y), C8*(O1.x+O1.y))
                       : make_float2(C8*(O1.x+O1.y), C8*(O1.y-O1.x));
    float2 W2 = (SGN>0)? make_float2(-O2.y, O2.x) : make_float2(O2.y, -O2.x);
    float2 W3 = (SGN>0)? make_float2(C8*(-O3.x-O3.y), C8*(O3.x-O3.y))
                       : make_float2(C8*(O3.y-O3.x), C8*(-O3.x-O3.y));
    a[0]=cadd(E0,O0); a[4]=csub(E0,O0);
    a[1]=cadd(E1,W1); a[5]=csub(E1,W1);
    a[2]=cadd(E2,W2); a[6]=csub(E2,W2);
    a[3]=cadd(E3,W3); a[7]=csub(E3,W3);
}

// apply w^k, k=1..7, log-depth tree
__device__ __forceinline__ void twid_apply(float2* v, float2 w1){
    float2 w2=cmul(w1,w1);
    float2 w3=cmul(w2,w1), w4=cmul(w2,w2);
    float2 w5=cmul(w2,w3), w6=cmul(w3,w3), w7=cmul(w3,w4);
    v[1]=cmul(v[1],w1); v[2]=cmul(v[2],w2); v[3]=cmul(v[3],w3);
    v[4]=cmul(v[4],w4); v[5]=cmul(v[5],w5); v[6]=cmul(v[6],w6); v[7]=cmul(v[7],w7);
}

// tanh-form GELU
__device__ __forceinline__ float gelu_fast(float v){
    float z = v*(0.7978845608028654f + 0.0356774081363001f*v*v);
    float e = __builtin_amdgcn_exp2f(-2.8853900817779268f * z);
    return v / (1.0f + e);
}

// Kernel 1: TWO rows per workgroup (dual independent dep-chains per wave).
__global__ __launch_bounds__(512, 4) void k1_row(
    const float* __restrict__ xr, const float* __restrict__ xi,
    const float* __restrict__ gamma, const float* __restrict__ beta,
    float* __restrict__ outR, float* __restrict__ outI)
{
    __shared__ float2 buf[2][4096];  // 64 KiB
    __shared__ float2 T[1024];       // 8 KiB: e^{+2pi i m/4096}

    const int t    = threadIdx.x;
    const int row0 = blockIdx.x * 2;

    for (int i = t; i < 1024; i += 512) {
        float s, c;
        sincosf((float)(kTwoPi/4096.0 * (double)i), &s, &c);
        T[i] = make_float2(c, s);
    }
    __syncthreads();

    const float2 E = make_float2(0.9999997058628822f, 7.669903187427045e-4f); // e^{+i pi/4096}
    const int l  = t & 63;
    const int s64 = ((t>>6)*512 + l) ^ (l>>4);
    const int u = t & 7, G = t >> 3, g = G & 7;
    const int s8 = (G<<6) + (g<<3) + (u ^ ((G&1)<<2));
    const int s1 = (t<<3) ^ ((t>>1)&7) ^ (((t>>3)&7)<<3);
    const int s0 = swz(t);

    float2 v0[8], v1[8];

    // ---- pre-combine (0.5s dropped; instnorm absorbs scale) + DIF h=512 ----
    #pragma unroll
    for (int r = 0; r < 2; ++r) {
        float2* v = r ? v1 : v0;
        const float* rR = xr + (size_t)(row0+r) * kN;
        const float* rI = xi + (size_t)(row0+r) * kN;
        #pragma unroll
        for (int j = 0; j < 8; ++j) {
            int k = t + (j<<9);
            float2 Xk  = make_float2(rR[k], rI[k]);
            int km  = (kN - k) & (kN-1);
            float2 Xm  = make_float2(rR[km], rI[km]);
            float2 Hk  = make_float2(Xk.x+Xm.x, Xk.y-Xm.y);          // 2*H[k]
            float2 Xk2 = make_float2(rR[k+4096], rI[k+4096]);
            int km2 = 4096 - k;
            float2 Xm2 = make_float2(rR[km2], rI[km2]);
            float2 Hk2 = make_float2(Xk2.x+Xm2.x, Xk2.y-Xm2.y);      // 2*H[k+4096]
            float2 S = cadd(Hk,Hk2), D = csub(Hk,Hk2);
            float2 w = W2048(T, k>>1);
            if (t & 1) w = cmul(w, E);
            float2 P = cmul(D, w);
            v[j] = make_float2(S.x - P.y, S.y + P.x);   // 2*Z[k]
        }
        dft8<1>(v);
        twid_apply(v, T[t]);
        #pragma unroll
        for (int j = 0; j < 8; ++j) buf[r][s0 + (j<<9)] = v[j];
    }
    __syncthreads();

    // ---- DIF h=64 ----
    #pragma unroll
    for (int j = 0; j < 8; ++j) v0[j] = buf[0][s64 ^ ((j<<6)|(j<<3)|((j&1)<<2))];
    #pragma unroll
    for (int j = 0; j < 8; ++j) v1[j] = buf[1][s64 ^ ((j<<6)|(j<<3)|((j&1)<<2))];
    dft8<1>(v0); twid_apply(v0, T[l<<3]);
    #pragma unroll
    for (int j = 0; j < 8; ++j) buf[0][s64 ^ ((j<<6)|(j<<3)|((j&1)<<2))] = v0[j];
    dft8<1>(v1); twid_apply(v1, T[l<<3]);
    #pragma unroll
    for (int j = 0; j < 8; ++j) buf[1][s64 ^ ((j<<6)|(j<<3)|((j&1)<<2))] = v1[j];
    __syncthreads();

    // ---- DIF h=8 ----
    #pragma unroll
    for (int j = 0; j < 8; ++j) v0[j] = buf[0][s8 ^ ((j<<3)|(j>>1))];
    #pragma unroll
    for (int j = 0; j < 8; ++j) v1[j] = buf[1][s8 ^ ((j<<3)|(j>>1))];
    dft8<1>(v0); twid_apply(v0, T[u<<6]);
    #pragma unroll
    for (int j = 0; j < 8; ++j) buf[0][s8 ^ ((j<<3)|(j>>1))] = v0[j];
    dft8<1>(v1); twid_apply(v1, T[u<<6]);
    #pragma unroll
    for (int j = 0; j < 8; ++j) buf[1][s8 ^ ((j<<3)|(j>>1))] = v1[j];
    __syncthreads();

    // ---- DIF h=1 (stays in regs) ----
    #pragma unroll
    for (int j = 0; j < 8; ++j) v0[j] = buf[0][s1 ^ j];
    #pragma unroll
    for (int j = 0; j < 8; ++j) v1[j] = buf[1][s1 ^ j];
    dft8<1>(v0);
    dft8<1>(v1);

    // ---- instance norm + GELU (order-agnostic) ----
    float ps0 = 0.f, pq0 = 0.f, ps1 = 0.f, pq1 = 0.f;
    #pragma unroll
    for (int j = 0; j < 8; ++j) {
        ps0 += v0[j].x + v0[j].y;  pq0 += v0[j].x*v0[j].x + v0[j].y*v0[j].y;
        ps1 += v1[j].x + v1[j].y;  pq1 += v1[j].x*v1[j].x + v1[j].y*v1[j].y;
    }
    #pragma unroll
    for (int off = 32; off >= 1; off >>= 1) {
        ps0 += __shfl_down(ps0, off);  pq0 += __shfl_down(pq0, off);
        ps1 += __shfl_down(ps1, off);  pq1 += __shfl_down(pq1, off);
    }
    // leader writes its OWN h1 slot (swz(512w)=512w): no pre-barrier needed
    if ((t & 63) == 0) {
        buf[0][(t>>6)<<9] = make_float2(ps0, pq0);
        buf[1][(t>>6)<<9] = make_float2(ps1, pq1);
    }
    __syncthreads();
    float sum0=0.f, sq0=0.f, sum1=0.f, sq1=0.f;
    #pragma unroll
    for (int w = 0; w < 8; ++w) {
        float2 p0 = buf[0][w<<9]; sum0 += p0.x; sq0 += p0.y;
        float2 p1 = buf[1][w<<9]; sum1 += p1.x; sq1 += p1.y;
    }
    __syncthreads();   // partial reads done before DIT h=1 stores
    {
        float mean = sum0 * (1.0f/8192.0f);
        float var  = sq0  * (1.0f/8192.0f) - mean*mean;
        float gg = gamma[row0 & (kC-1)] * rsqrtf(var + 1e-5f);
        float bb = beta[row0 & (kC-1)] - mean * gg;
        #pragma unroll
        for (int j = 0; j < 8; ++j) {
            v0[j].x = gelu_fast(v0[j].x * gg + bb);
            v0[j].y = gelu_fast(v0[j].y * gg + bb);
        }
    }
    {
        float mean = sum1 * (1.0f/8192.0f);
        float var  = sq1  * (1.0f/8192.0f) - mean*mean;
        float gg = gamma[(row0+1) & (kC-1)] * rsqrtf(var + 1e-5f);
        float bb = beta[(row0+1) & (kC-1)] - mean * gg;
        #pragma unroll
        for (int j = 0; j < 8; ++j) {
            v1[j].x = gelu_fast(v1[j].x * gg + bb);
            v1[j].y = gelu_fast(v1[j].y * gg + bb);
        }
    }

    // ---- forward: DIT h=1 ----
    dft8<-1>(v0);
    dft8<-1>(v1);
    #pragma unroll
    for (int j = 0; j < 8; ++j) buf[0][s1 ^ j] = v0[j];
    #pragma unroll
    for (int j = 0; j < 8; ++j) buf[1][s1 ^ j] = v1[j];
    __syncthreads();

    // ---- DIT h=8 ----
    #pragma unroll
    for (int j = 0; j < 8; ++j) v0[j] = buf[0][s8 ^ ((j<<3)|(j>>1))];
    #pragma unroll
    for (int j = 0; j < 8; ++j) v1[j] = buf[1][s8 ^ ((j<<3)|(j>>1))];
    twid_apply(v0, cconj(T[u<<6])); dft8<-1>(v0);
    #pragma unroll
    for (int j = 0; j < 8; ++j) buf[0][s8 ^ ((j<<3)|(j>>1))] = v0[j];
    twid_apply(v1, cconj(T[u<<6])); dft8<-1>(v1);
    #pragma unroll
    for (int j = 0; j < 8; ++j) buf[1][s8 ^ ((j<<3)|(j>>1))] = v1[j];
    __syncthreads();

    // ---- DIT h=64 ----
    #pragma unroll
    for (int j = 0; j < 8; ++j) v0[j] = buf[0][s64 ^ ((j<<6)|(j<<3)|((j&1)<<2))];
    #pragma unroll
    for (int j = 0; j < 8; ++j) v1[j] = buf[1][s64 ^ ((j<<6)|(j<<3)|((j&1)<<2))];
    twid_apply(v0, cconj(T[l<<3])); dft8<-1>(v0);
    #pragma unroll
    for (int j = 0; j < 8; ++j) buf[0][s64 ^ ((j<<6)|(j<<3)|((j&1)<<2))] = v0[j];
    twid_apply(v1, cconj(T[l<<3])); dft8<-1>(v1);
    #pragma unroll
    for (int j = 0; j < 8; ++j) buf[1][s64 ^ ((j<<6)|(j<<3)|((j&1)<<2))] = v1[j];
    __syncthreads();

    // ---- DIT h=512 (natural order out; stored for mirror access) ----
    #pragma unroll
    for (int j = 0; j < 8; ++j) v0[j] = buf[0][s0 + (j<<9)];
    #pragma unroll
    for (int j = 0; j < 8; ++j) v1[j] = buf[1][s0 + (j<<9)];
    twid_apply(v0, cconj(T[t])); dft8<-1>(v0);
    #pragma unroll
    for (int j = 0; j < 8; ++j) buf[0][s0 + (j<<9)] = v0[j];
    twid_apply(v1, cconj(T[t])); dft8<-1>(v1);
    #pragma unroll
    for (int j = 0; j < 8; ++j) buf[1][s0 + (j<<9)] = v1[j];
    __syncthreads();

    // ---- post-combine (0.5s dropped -> 2*Y; folded into k2 scale) ----
    #pragma unroll
    for (int r = 0; r < 2; ++r) {
        float2* v = r ? v1 : v0;
        float* oR = outR + (size_t)(row0+r) * kN;
        float* oI = outI + (size_t)(row0+r) * kN;
        #pragma unroll
        for (int j = 0; j < 8; ++j) {
            int k = t + (j<<9);
            float2 Z  = v[j];
            float2 Zm = buf[r][swz((4096 - k) & 4095)];
            float2 S = make_float2(Z.x+Zm.x, Z.y-Zm.y);
            float2 D = make_float2(Z.x-Zm.x, Z.y+Zm.y);
            float2 w = W2048(T, k>>1);
            if (t & 1) w = cmul(w, E);
            w = cconj(w);
            float2 P = cmul(D, w);
            oR[k] = S.x + P.y;
            oI[k] = S.y - P.x;
        }
        if (t == 0) {
            oR[4096] = 2.0f*(v[0].x - v[0].y);   // 2*(Re Z'[0] - Im Z'[0])
            oI[4096] = 0.f;
        }
    }
}

// Kernel 2: per (b, 32-wide k tile), kk in [0,4096]: 128-pt FFT along c,
// scale (incl. folded 0.5), bin rules, conjugate-mirror writes.
__global__ __launch_bounds__(256,4) void k2_col(float* __restrict__ outR,
                                                float* __restrict__ outI)
{
    __shared__ float2 tile[kC][32];  // 32 KiB
    __shared__ float2 tw[64];

    const int tid = threadIdx.x;
    const int k   = tid & 31;
    const int g   = tid >> 5;        // 0..7
    const int b   = blockIdx.y;
    const int kk  = (blockIdx.x << 5) + k;
    const bool valid = (kk <= 4096);

    if (tid < 64) {
        float s, c;
        sincosf((float)(kTwoPi/128.0 * (double)tid), &s, &c);
        tw[tid] = make_float2(c, -s);
    }
    float* baseR = outR + (size_t)b * kC * kN;
    float* baseI = outI + (size_t)b * kC * kN;
    for (int c = g; c < kC; c += 8) {
        size_t off = (size_t)c * kN + kk;
        tile[c][k] = valid ? make_float2(baseR[off], baseI[off])
                           : make_float2(0.f, 0.f);
    }
    __syncthreads();

    for (int st = 7; st >= 1; --st) {
        const int h = 1 << (st-1);
        #pragma unroll
        for (int s = 0; s < 8; ++s) {
            int q   = g + (s<<3);
            int pos = q & (h-1);
            int i0  = ((q >> (st-1)) << st) + pos;
            int i1  = i0 + h;
            float2 a = tile[i0][k], bb = tile[i1][k];
            float2 w = tw[pos << (7-st)];
            tile[i0][k] = cadd(a, bb);
            tile[i1][k] = cmul(csub(a, bb), w);
        }
        __syncthreads();
    }

    if (valid) {
        for (int p = g; p < kC; p += 8) {
            int f = (int)(__brev((unsigned)p) >> 25);
            float2 v = tile[p][k];
            v.x *= kScale; v.y *= kScale;
            size_t off = (size_t)f * kN + kk;
            if (kk == 0 || kk == 4096) {
                baseR[off] = v.x; baseI[off] = 0.f;
            } else {
                baseR[off] = v.x; baseI[off] = v.y;
                size_t offm = (size_t)f * kN + (kN - kk);
                baseR[offm] = v.x; baseI[offm] = -v.y;
            }
        }
    }
}

extern "C" void kernel_launch(void* const* d_in, const int* in_sizes, int n_in,
                              void* d_out, int out_size, void* d_ws, size_t ws_size,
                              hipStream_t stream)
{
    const float* xr    = (const float*)d_in[0];
    const float* xi    = (const float*)d_in[1];
    const float* gamma = (const float*)d_in[2];
    const float* beta  = (const float*)d_in[3];

    float* outR = (float*)d_out;
    float* outI = outR + (size_t)kB * kC * kN;

    k1_row<<<kB * kC / 2, 512, 0, stream>>>(xr, xi, gamma, beta, outR, outI);
    k2_col<<<dim3(129, kB), 256, 0, stream>>>(outR, outI);
}

// Round 5
// 122.715 us; speedup vs baseline: 3.0402x; 1.0153x over previous
//
#include <hip/hip_runtime.h>
#include <math.h>

static constexpr int kN = 8192;
static constexpr int kC = 128;
static constexpr int kB = 16;
static constexpr float kScale = 0.5f / 1048576.0f; // 1/(C*N) * 0.5 (post-combine fold)
static constexpr double kTwoPi = 6.28318530717958647692;

#define C8 0.70710678118654752f

__device__ __forceinline__ float2 cadd(float2 a, float2 b){ return make_float2(a.x+b.x, a.y+b.y); }
__device__ __forceinline__ float2 csub(float2 a, float2 b){ return make_float2(a.x-b.x, a.y-b.y); }
__device__ __forceinline__ float2 cmul(float2 a, float2 b){ return make_float2(a.x*b.x-a.y*b.y, a.x*b.y+a.y*b.x); }
__device__ __forceinline__ float2 cconj(float2 a){ return make_float2(a.x, -a.y); }

// conflict-floor swizzle (validated r3/r4)
__device__ __forceinline__ int swz(int n){ return n ^ ((n>>4)&7) ^ (((n>>6)&7)<<3); }

// e^{+2pi i m/4096}, m in [0,2048)
__device__ __forceinline__ float2 W2048(const float2* T, int m){
    float2 tt = T[m & 1023];
    return (m & 1024) ? make_float2(-tt.y, tt.x) : tt;
}

// 8-point DFT, A_k = sum_j a_j e^{SGN*2pi i jk/8}, in place
template<int SGN>
__device__ __forceinline__ void dft8(float2* a){
    float2 s0=cadd(a[0],a[4]), s1=csub(a[0],a[4]);
    float2 s2=cadd(a[2],a[6]), s3=csub(a[2],a[6]);
    float2 E0=cadd(s0,s2), E2=csub(s0,s2);
    float2 j3 = (SGN>0)? make_float2(-s3.y, s3.x) : make_float2(s3.y, -s3.x);
    float2 E1=cadd(s1,j3), E3=csub(s1,j3);
    float2 t0=cadd(a[1],a[5]), t1=csub(a[1],a[5]);
    float2 t2=cadd(a[3],a[7]), t3=csub(a[3],a[7]);
    float2 O0=cadd(t0,t2), O2=csub(t0,t2);
    float2 k3 = (SGN>0)? make_float2(-t3.y, t3.x) : make_float2(t3.y, -t3.x);
    float2 O1=cadd(t1,k3), O3=csub(t1,k3);
    float2 W1 = (SGN>0)? make_float2(C8*(O1.x-O1.y), C8*(O1.x+O1.y))
                       : make_float2(C8*(O1.x+O1.y), C8*(O1.y-O1.x));
    float2 W2 = (SGN>0)? make_float2(-O2.y, O2.x) : make_float2(O2.y, -O2.x);
    float2 W3 = (SGN>0)? make_float2(C8*(-O3.x-O3.y), C8*(O3.x-O3.y))
                       : make_float2(C8*(O3.y-O3.x), C8*(-O3.x-O3.y));
    a[0]=cadd(E0,O0); a[4]=csub(E0,O0);
    a[1]=cadd(E1,W1); a[5]=csub(E1,W1);
    a[2]=cadd(E2,W2); a[6]=csub(E2,W2);
    a[3]=cadd(E3,W3); a[7]=csub(E3,W3);
}

// apply w^k, k=1..7, to BOTH rows; tree built once
__device__ __forceinline__ void twid_apply2(float2* a, float2* b, float2 w1){
    float2 w2=cmul(w1,w1);
    float2 w3=cmul(w2,w1), w4=cmul(w2,w2);
    float2 w5=cmul(w2,w3), w6=cmul(w3,w3), w7=cmul(w3,w4);
    a[1]=cmul(a[1],w1); a[2]=cmul(a[2],w2); a[3]=cmul(a[3],w3);
    a[4]=cmul(a[4],w4); a[5]=cmul(a[5],w5); a[6]=cmul(a[6],w6); a[7]=cmul(a[7],w7);
    b[1]=cmul(b[1],w1); b[2]=cmul(b[2],w2); b[3]=cmul(b[3],w3);
    b[4]=cmul(b[4],w4); b[5]=cmul(b[5],w5); b[6]=cmul(b[6],w6); b[7]=cmul(b[7],w7);
}

// tanh-form GELU
__device__ __forceinline__ float gelu_fast(float v){
    float z = v*(0.7978845608028654f + 0.0356774081363001f*v*v);
    float e = __builtin_amdgcn_exp2f(-2.8853900817779268f * z);
    return v / (1.0f + e);
}

// Kernel 1: TWO rows per workgroup, PACKED as float4 in LDS:
// buf[n] = (row0.re, row0.im, row1.re, row1.im) -> all exchanges are b128.
__global__ __launch_bounds__(512, 4) void k1_row(
    const float* __restrict__ xr, const float* __restrict__ xi,
    const float* __restrict__ gamma, const float* __restrict__ beta,
    float* __restrict__ outR, float* __restrict__ outI)
{
    __shared__ float4 buf[4096];  // 64 KiB packed row-pair
    __shared__ float2 T[1024];    // 8 KiB: e^{+2pi i m/4096}

    const int t    = threadIdx.x;
    const int row0 = blockIdx.x * 2;

    for (int i = t; i < 1024; i += 512) {
        float s, c;
        sincosf((float)(kTwoPi/4096.0 * (double)i), &s, &c);
        T[i] = make_float2(c, s);
    }
    __syncthreads();

    const float2 E = make_float2(0.9999997058628822f, 7.669903187427045e-4f); // e^{+i pi/4096}
    const int l   = t & 63;
    const int s64 = ((t>>6)*512 + l) ^ (l>>4);
    const int u = t & 7, G = t >> 3, g = G & 7;
    const int s8 = (G<<6) + (g<<3) + (u ^ ((G&1)<<2));
    const int s1 = (t<<3) ^ ((t>>1)&7) ^ (((t>>3)&7)<<3);
    const int s0 = swz(t);

    float2 v0[8], v1[8];

    const float* r0R = xr + (size_t)row0 * kN;
    const float* r0I = xi + (size_t)row0 * kN;
    const float* r1R = r0R + kN;
    const float* r1I = r0I + kN;

    // ---- pre-combine (scale-free) + DIF h=512 ----
    #pragma unroll
    for (int j = 0; j < 8; ++j) {
        int k   = t + (j<<9);
        int km  = (kN - k) & (kN-1);
        int km2 = 4096 - k;
        float2 w = W2048(T, k>>1);
        if (t & 1) w = cmul(w, E);
        {
            float2 Hk  = make_float2(r0R[k]+r0R[km],       r0I[k]-r0I[km]);
            float2 Hk2 = make_float2(r0R[k+4096]+r0R[km2], r0I[k+4096]-r0I[km2]);
            float2 S = cadd(Hk,Hk2), D = csub(Hk,Hk2);
            float2 P = cmul(D, w);
            v0[j] = make_float2(S.x - P.y, S.y + P.x);
        }
        {
            float2 Hk  = make_float2(r1R[k]+r1R[km],       r1I[k]-r1I[km]);
            float2 Hk2 = make_float2(r1R[k+4096]+r1R[km2], r1I[k+4096]-r1I[km2]);
            float2 S = cadd(Hk,Hk2), D = csub(Hk,Hk2);
            float2 P = cmul(D, w);
            v1[j] = make_float2(S.x - P.y, S.y + P.x);
        }
    }
    dft8<1>(v0); dft8<1>(v1);
    twid_apply2(v0, v1, T[t]);
    #pragma unroll
    for (int j = 0; j < 8; ++j)
        buf[s0 + (j<<9)] = make_float4(v0[j].x, v0[j].y, v1[j].x, v1[j].y);
    __syncthreads();

    // ---- DIF h=64 ----
    #pragma unroll
    for (int j = 0; j < 8; ++j) {
        float4 p = buf[s64 ^ ((j<<6)|(j<<3)|((j&1)<<2))];
        v0[j] = make_float2(p.x, p.y); v1[j] = make_float2(p.z, p.w);
    }
    dft8<1>(v0); dft8<1>(v1);
    twid_apply2(v0, v1, T[l<<3]);
    #pragma unroll
    for (int j = 0; j < 8; ++j)
        buf[s64 ^ ((j<<6)|(j<<3)|((j&1)<<2))] = make_float4(v0[j].x, v0[j].y, v1[j].x, v1[j].y);
    __syncthreads();

    // ---- DIF h=8 ----
    #pragma unroll
    for (int j = 0; j < 8; ++j) {
        float4 p = buf[s8 ^ ((j<<3)|(j>>1))];
        v0[j] = make_float2(p.x, p.y); v1[j] = make_float2(p.z, p.w);
    }
    dft8<1>(v0); dft8<1>(v1);
    twid_apply2(v0, v1, T[u<<6]);
    #pragma unroll
    for (int j = 0; j < 8; ++j)
        buf[s8 ^ ((j<<3)|(j>>1))] = make_float4(v0[j].x, v0[j].y, v1[j].x, v1[j].y);
    __syncthreads();

    // ---- DIF h=1 (stays in regs) ----
    #pragma unroll
    for (int j = 0; j < 8; ++j) {
        float4 p = buf[s1 ^ j];
        v0[j] = make_float2(p.x, p.y); v1[j] = make_float2(p.z, p.w);
    }
    dft8<1>(v0); dft8<1>(v1);

    // ---- instance norm + GELU (order-agnostic) ----
    float ps0 = 0.f, pq0 = 0.f, ps1 = 0.f, pq1 = 0.f;
    #pragma unroll
    for (int j = 0; j < 8; ++j) {
        ps0 += v0[j].x + v0[j].y;  pq0 += v0[j].x*v0[j].x + v0[j].y*v0[j].y;
        ps1 += v1[j].x + v1[j].y;  pq1 += v1[j].x*v1[j].x + v1[j].y*v1[j].y;
    }
    #pragma unroll
    for (int off = 32; off >= 1; off >>= 1) {
        ps0 += __shfl_down(ps0, off);  pq0 += __shfl_down(pq0, off);
        ps1 += __shfl_down(ps1, off);  pq1 += __shfl_down(pq1, off);
    }
    // leader writes its OWN h1 slot (s1(64w)^0 = 512w): no pre-barrier needed
    if ((t & 63) == 0) buf[(t>>6)<<9] = make_float4(ps0, pq0, ps1, pq1);
    __syncthreads();
    float sum0=0.f, sq0=0.f, sum1=0.f, sq1=0.f;
    #pragma unroll
    for (int w = 0; w < 8; ++w) {
        float4 p = buf[w<<9];
        sum0 += p.x; sq0 += p.y; sum1 += p.z; sq1 += p.w;
    }
    __syncthreads();   // partial reads done before DIT h=1 stores
    {
        float mean = sum0 * (1.0f/8192.0f);
        float var  = sq0  * (1.0f/8192.0f) - mean*mean;
        float gg = gamma[row0 & (kC-1)] * rsqrtf(var + 1e-5f);
        float bb = beta[row0 & (kC-1)] - mean * gg;
        #pragma unroll
        for (int j = 0; j < 8; ++j) {
            v0[j].x = gelu_fast(v0[j].x * gg + bb);
            v0[j].y = gelu_fast(v0[j].y * gg + bb);
        }
    }
    {
        float mean = sum1 * (1.0f/8192.0f);
        float var  = sq1  * (1.0f/8192.0f) - mean*mean;
        float gg = gamma[(row0+1) & (kC-1)] * rsqrtf(var + 1e-5f);
        float bb = beta[(row0+1) & (kC-1)] - mean * gg;
        #pragma unroll
        for (int j = 0; j < 8; ++j) {
            v1[j].x = gelu_fast(v1[j].x * gg + bb);
            v1[j].y = gelu_fast(v1[j].y * gg + bb);
        }
    }

    // ---- forward: DIT h=1 ----
    dft8<-1>(v0); dft8<-1>(v1);
    #pragma unroll
    for (int j = 0; j < 8; ++j)
        buf[s1 ^ j] = make_float4(v0[j].x, v0[j].y, v1[j].x, v1[j].y);
    __syncthreads();

    // ---- DIT h=8 ----
    #pragma unroll
    for (int j = 0; j < 8; ++j) {
        float4 p = buf[s8 ^ ((j<<3)|(j>>1))];
        v0[j] = make_float2(p.x, p.y); v1[j] = make_float2(p.z, p.w);
    }
    twid_apply2(v0, v1, cconj(T[u<<6]));
    dft8<-1>(v0); dft8<-1>(v1);
    #pragma unroll
    for (int j = 0; j < 8; ++j)
        buf[s8 ^ ((j<<3)|(j>>1))] = make_float4(v0[j].x, v0[j].y, v1[j].x, v1[j].y);
    __syncthreads();

    // ---- DIT h=64 ----
    #pragma unroll
    for (int j = 0; j < 8; ++j) {
        float4 p = buf[s64 ^ ((j<<6)|(j<<3)|((j&1)<<2))];
        v0[j] = make_float2(p.x, p.y); v1[j] = make_float2(p.z, p.w);
    }
    twid_apply2(v0, v1, cconj(T[l<<3]));
    dft8<-1>(v0); dft8<-1>(v1);
    #pragma unroll
    for (int j = 0; j < 8; ++j)
        buf[s64 ^ ((j<<6)|(j<<3)|((j&1)<<2))] = make_float4(v0[j].x, v0[j].y, v1[j].x, v1[j].y);
    __syncthreads();

    // ---- DIT h=512 (natural order out; stored for mirror access) ----
    #pragma unroll
    for (int j = 0; j < 8; ++j) {
        float4 p = buf[s0 + (j<<9)];
        v0[j] = make_float2(p.x, p.y); v1[j] = make_float2(p.z, p.w);
    }
    twid_apply2(v0, v1, cconj(T[t]));
    dft8<-1>(v0); dft8<-1>(v1);
    #pragma unroll
    for (int j = 0; j < 8; ++j)
        buf[s0 + (j<<9)] = make_float4(v0[j].x, v0[j].y, v1[j].x, v1[j].y);
    __syncthreads();

    // ---- post-combine (2*Y; 0.5s folded into k2 scale); both rows per j ----
    float* o0R = outR + (size_t)row0 * kN;
    float* o0I = outI + (size_t)row0 * kN;
    float* o1R = o0R + kN;
    float* o1I = o0I + kN;
    #pragma unroll
    for (int j = 0; j < 8; ++j) {
        int k = t + (j<<9);
        float4 pm = buf[swz((4096 - k) & 4095)];
        float2 w = W2048(T, k>>1);
        if (t & 1) w = cmul(w, E);
        w = cconj(w);
        {
            float2 Z = v0[j], Zm = make_float2(pm.x, pm.y);
            float2 S = make_float2(Z.x+Zm.x, Z.y-Zm.y);
            float2 D = make_float2(Z.x-Zm.x, Z.y+Zm.y);
            float2 P = cmul(D, w);
            o0R[k] = S.x + P.y;
            o0I[k] = S.y - P.x;
        }
        {
            float2 Z = v1[j], Zm = make_float2(pm.z, pm.w);
            float2 S = make_float2(Z.x+Zm.x, Z.y-Zm.y);
            float2 D = make_float2(Z.x-Zm.x, Z.y+Zm.y);
            float2 P = cmul(D, w);
            o1R[k] = S.x + P.y;
            o1I[k] = S.y - P.x;
        }
    }
    if (t == 0) {
        o0R[4096] = 2.0f*(v0[0].x - v0[0].y);  // 2*(Re Z'[0] - Im Z'[0])
        o0I[4096] = 0.f;
        o1R[4096] = 2.0f*(v1[0].x - v1[0].y);
        o1I[4096] = 0.f;
    }
}

// Kernel 2: per (b, 32-wide k tile), kk in [0,4096]: 128-pt FFT along c,
// scale (incl. folded 0.5), bin rules, conjugate-mirror writes. (~HBM roofline)
__global__ __launch_bounds__(256,4) void k2_col(float* __restrict__ outR,
                                                float* __restrict__ outI)
{
    __shared__ float2 tile[kC][32];  // 32 KiB
    __shared__ float2 tw[64];

    const int tid = threadIdx.x;
    const int k   = tid & 31;
    const int g   = tid >> 5;        // 0..7
    const int b   = blockIdx.y;
    const int kk  = (blockIdx.x << 5) + k;
    const bool valid = (kk <= 4096);

    if (tid < 64) {
        float s, c;
        sincosf((float)(kTwoPi/128.0 * (double)tid), &s, &c);
        tw[tid] = make_float2(c, -s);
    }
    float* baseR = outR + (size_t)b * kC * kN;
    float* baseI = outI + (size_t)b * kC * kN;
    for (int c = g; c < kC; c += 8) {
        size_t off = (size_t)c * kN + kk;
        tile[c][k] = valid ? make_float2(baseR[off], baseI[off])
                           : make_float2(0.f, 0.f);
    }
    __syncthreads();

    for (int st = 7; st >= 1; --st) {
        const int h = 1 << (st-1);
        #pragma unroll
        for (int s = 0; s < 8; ++s) {
            int q   = g + (s<<3);
            int pos = q & (h-1);
            int i0  = ((q >> (st-1)) << st) + pos;
            int i1  = i0 + h;
            float2 a = tile[i0][k], bb = tile[i1][k];
            float2 w = tw[pos << (7-st)];
            tile[i0][k] = cadd(a, bb);
            tile[i1][k] = cmul(csub(a, bb), w);
        }
        __syncthreads();
    }

    if (valid) {
        for (int p = g; p < kC; p += 8) {
            int f = (int)(__brev((unsigned)p) >> 25);
            float2 v = tile[p][k];
            v.x *= kScale; v.y *= kScale;
            size_t off = (size_t)f * kN + kk;
            if (kk == 0 || kk == 4096) {
                baseR[off] = v.x; baseI[off] = 0.f;
            } else {
                baseR[off] = v.x; baseI[off] = v.y;
                size_t offm = (size_t)f * kN + (kN - kk);
                baseR[offm] = v.x; baseI[offm] = -v.y;
            }
        }
    }
}

extern "C" void kernel_launch(void* const* d_in, const int* in_sizes, int n_in,
                              void* d_out, int out_size, void* d_ws, size_t ws_size,
                              hipStream_t stream)
{
    const float* xr    = (const float*)d_in[0];
    const float* xi    = (const float*)d_in[1];
    const float* gamma = (const float*)d_in[2];
    const float* beta  = (const float*)d_in[3];

    float* outR = (float*)d_out;
    float* outI = outR + (size_t)kB * kC * kN;

    k1_row<<<kB * kC / 2, 512, 0, stream>>>(xr, xi, gamma, beta, outR, outI);
    k2_col<<<dim3(129, kB), 256, 0, stream>>>(outR, outI);
}